// Round 7
// baseline (538.811 us; speedup 1.0000x reference)
//
#include <hip/hip_runtime.h>
#include <cstdint>
#include <cstddef>

// ---------------------------------------------------------------------------
// AffineMultiQueryHardAttentionEncoder
//   scores[m] = max_n ( (q[n]*a) . k[m] ), top-64, softmax, sum w_i * V[idx_i]
// R7: split regimes.
//   - prep_keys: streaming LDS-transpose converter. Linear 2KB-burst reads,
//     linear 16KB-burst writes -> kstage [mb][ks=32][row=64][64B] bf16,
//     chunk-XOR pre-applied (glds-ready).  ~615MB clean streaming.
//   - scores_gemm: A+B both global_load_lds, true 1-ahead dbuf, 72KB LDS,
//     VGPR<=128 -> 2 blocks/CU (m114 overlap covers barrier drains).
//   - select: hist threshold + exact f32 rescore + final (unchanged).
// ---------------------------------------------------------------------------

typedef __attribute__((ext_vector_type(8))) short bf16x8;
typedef __attribute__((ext_vector_type(4))) float f32x4;

static constexpr int NQ = 512;
static constexpr int DD = 1024;
static constexpr int MK = 100000;
static constexpr int BM = 64;
static constexpr int NKK = DD / 32;                 // 32 K-steps (BK=32)
static constexpr int MBLOCKS = (MK + BM - 1) / BM;  // 1563
static constexpr int CAP = 1024;

// workspace layout (bytes)
static constexpr size_t KSTAGE_OFF   = 0;   // [1563][32][64][64B] = 204,865,536
static constexpr size_t KSTAGE_BYTES = (size_t)MBLOCKS * 131072;
static constexpr size_t QSTAGE_OFF   = KSTAGE_OFF + KSTAGE_BYTES;   // [32][512][64B] = 1 MiB
static constexpr size_t QSTAGE_BYTES = (size_t)NKK * NQ * 64;
static constexpr size_t SCORES_OFF   = QSTAGE_OFF + QSTAGE_BYTES;
static constexpr size_t SCORES_BYTES = (size_t)MBLOCKS * BM * sizeof(float);
static constexpr size_t CIDX_OFF     = SCORES_OFF + SCORES_BYTES;
static constexpr size_t RESC_OFF     = CIDX_OFF + (size_t)CAP * 4;
static constexpr size_t CNT_OFF      = RESC_OFF + (size_t)CAP * 4;
static constexpr size_t HIST_OFF     = CNT_OFF + 64;
static constexpr size_t VLO_OFF      = HIST_OFF + 8192 * 4;

// gemm LDS: A dbuf 2x[64][64B]=8KB @0 ; B dbuf 2x[512][64B]=64KB @8192
static constexpr int AOFF = 0;
static constexpr int BOFF = 8192;
static constexpr int GEMM_LDS = 8192 + 2 * 32768;    // 73728 -> 2 blocks/CU
static constexpr int PREP_LDS = 131072;              // full kstage tile image

static __device__ __forceinline__ unsigned short f32_to_bf16_rne(float f) {
    unsigned int u = __float_as_uint(f);
    unsigned int r = (u + 0x7FFFu + ((u >> 16) & 1u)) >> 16;
    return (unsigned short)r;
}
static __device__ __forceinline__ unsigned int xform(float f) {
    unsigned int u = __float_as_uint(f);
    return u ^ ((unsigned int)((int)u >> 31) | 0x80000000u);
}
static __device__ __forceinline__ float unxform(unsigned int u) {
    unsigned int b = (u & 0x80000000u) ? (u ^ 0x80000000u) : ~u;
    return __uint_as_float(b);
}

typedef __attribute__((address_space(1))) const unsigned int g1u32;
typedef __attribute__((address_space(3))) unsigned int l3u32;
static __device__ __forceinline__ void async16(const void* g, void* l) {
    __builtin_amdgcn_global_load_lds((g1u32*)g, (l3u32*)(uintptr_t)l, 16, 0, 0);
}

// ---------------------------------------------------------------------------
// prep_q: qa = q*a -> bf16 RNE, kk-granular pre-swizzled (R6 layout):
// chunk id = (kk*512 + row)*4 + c holds qa[row][kk*32 + (c^(row&3))*8 .. +7]
// ---------------------------------------------------------------------------
__global__ void prep_q(const float* __restrict__ q, const float* __restrict__ a,
                       unsigned short* __restrict__ qs) {
    int id  = blockIdx.x * 256 + threadIdx.x;   // 0..65535
    int c   = id & 3;
    int row = (id >> 2) & (NQ - 1);
    int kk  = id >> 11;
    int kb  = kk * 32 + ((c ^ (row & 3)) << 3);

    const float* qrow = q + (size_t)row * DD + kb;
    float4 v0 = *(const float4*)(qrow);
    float4 v1 = *(const float4*)(qrow + 4);
    float4 a0 = *(const float4*)(a + kb);
    float4 a1 = *(const float4*)(a + kb + 4);
    float f[8] = {v0.x * a0.x, v0.y * a0.y, v0.z * a0.z, v0.w * a0.w,
                  v1.x * a1.x, v1.y * a1.y, v1.z * a1.z, v1.w * a1.w};
    bf16x8 o;
#pragma unroll
    for (int j = 0; j < 8; ++j) o[j] = (short)f32_to_bf16_rne(f[j]);
    *(bf16x8*)(qs + (size_t)id * 8) = o;
}

// ---------------------------------------------------------------------------
// prep_keys: per-block 64-row tile, LDS transpose.
//   phase1: linear read keys (2KB/wave bursts), bf16, ds_write to the
//           kstage image: lds[ks*4096 + row*64 + ((c^(row&3))<<4)]
//   phase2: linear LDS read -> fully sequential 128KB global write
// ---------------------------------------------------------------------------
__launch_bounds__(1024)
__global__ void prep_keys(const float* __restrict__ keys,
                          unsigned short* __restrict__ kst) {
    extern __shared__ char lds[];
    const int mb = blockIdx.x;
    const int t  = threadIdx.x;
    const int col8 = t & 127;            // 8-f32 chunk within row
    const int rsub = t >> 7;             // 0..7

#pragma unroll
    for (int it = 0; it < 8; ++it) {
        const int row = it * 8 + rsub;
        const int gm  = mb * 64 + row;
        bf16x8 o;
        if (gm < MK) {
            const float* src = keys + (size_t)gm * DD + col8 * 8;
            float4 v0 = *(const float4*)(src);
            float4 v1 = *(const float4*)(src + 4);
            float f[8] = {v0.x, v0.y, v0.z, v0.w, v1.x, v1.y, v1.z, v1.w};
#pragma unroll
            for (int j = 0; j < 8; ++j) o[j] = (short)f32_to_bf16_rne(f[j]);
        } else {
#pragma unroll
            for (int j = 0; j < 8; ++j) o[j] = 0;
        }
        const int ks = col8 >> 2;
        const int c  = col8 & 3;
        *(bf16x8*)(lds + ks * 4096 + row * 64 + (((c ^ (row & 3))) << 4)) = o;
    }
    __syncthreads();

    char* dst = (char*)kst + (size_t)mb * 131072;
#pragma unroll
    for (int it = 0; it < 8; ++it) {
        const int off = it * 16384 + t * 16;
        *(f32x4*)(dst + off) = *(const f32x4*)(lds + off);
    }
}

// ---------------------------------------------------------------------------
// prescreen GEMM + column max: A+B via global_load_lds, 1-ahead dbuf
// ---------------------------------------------------------------------------
__launch_bounds__(512, 4)
__global__ void scores_gemm(const unsigned short* __restrict__ kstage,
                            const unsigned short* __restrict__ qs,
                            float* __restrict__ scores) {
    extern __shared__ char smem[];
    const int tid  = threadIdx.x;
    const int wid  = tid >> 6;
    const int lane = tid & 63;
    const int g    = lane >> 4;
    const int r16  = lane & 15;

    // bijective XCD swizzle (m204)
    const int nwg = gridDim.x;
    const int qq  = nwg >> 3, rr = nwg & 7;
    const int xcd = blockIdx.x & 7, loc = blockIdx.x >> 3;
    const int mb  = (xcd < rr ? xcd * (qq + 1) : rr * (qq + 1) + (xcd - rr) * qq) + loc;
    const int m0  = mb * BM;

    // staging sources (both pre-swizzled, linear)
    const char* asrc = (const char*)kstage + (size_t)mb * 131072
                     + (wid & 3) * 1024 + lane * 16;          // waves 0-3 only
    const char* bsrc = (const char*)qs + (size_t)(wid * 64) * 64 + (size_t)lane * 16;
    const int   bdst = BOFF + wid * 4096;   // + buf*32768 + i*1024
    const int   adst = AOFF + (wid & 3) * 1024;               // + buf*4096

    // fragment read offsets
    const int sw = ((g ^ (r16 & 3)) << 4);
    int arow_rd[4], brow_rd[4];
#pragma unroll
    for (int rt = 0; rt < 4; ++rt) arow_rd[rt] = AOFF + (rt * 16 + r16) * 64 + sw;
#pragma unroll
    for (int ct = 0; ct < 4; ++ct) brow_rd[ct] = BOFF + (wid * 64 + ct * 16 + r16) * 64 + sw;

    f32x4 acc[4][4] = {};

    // prologue: stage ks=0 into buf0
    if (wid < 4) async16(asrc, smem + adst);
#pragma unroll
    for (int i = 0; i < 4; ++i)
        async16(bsrc + i * 1024, smem + bdst + i * 1024);
    __syncthreads();

    for (int ks = 0; ks < NKK; ++ks) {
        const int cur = ks & 1, nxt = cur ^ 1;
        // 1-ahead prefetch: issued BEFORE compute so compute hides latency
        if (ks + 1 < NKK) {
            if (wid < 4) async16(asrc + (size_t)(ks + 1) * 4096, smem + nxt * 4096 + adst);
#pragma unroll
            for (int i = 0; i < 4; ++i)
                async16(bsrc + (size_t)(ks + 1) * 32768 + i * 1024,
                        smem + nxt * 32768 + bdst + i * 1024);
        }
        bf16x8 ah[4], bh[4];
#pragma unroll
        for (int rt = 0; rt < 4; ++rt)
            ah[rt] = *(const bf16x8*)(smem + cur * 4096 + arow_rd[rt]);
#pragma unroll
        for (int ct = 0; ct < 4; ++ct)
            bh[ct] = *(const bf16x8*)(smem + cur * 32768 + brow_rd[ct]);
        __builtin_amdgcn_s_setprio(1);
#pragma unroll
        for (int rt = 0; rt < 4; ++rt)
#pragma unroll
            for (int ct = 0; ct < 4; ++ct)
                acc[rt][ct] = __builtin_amdgcn_mfma_f32_16x16x32_bf16(ah[rt], bh[ct], acc[rt][ct], 0, 0, 0);
        __builtin_amdgcn_s_setprio(0);
        __syncthreads();
    }

    // epilogue: per-lane max over ct, shfl over 16 query-cols, cross-wave
    float* wmax = (float*)smem;   // [8][64], safe after final barrier
#pragma unroll
    for (int rt = 0; rt < 4; ++rt) {
#pragma unroll
        for (int r = 0; r < 4; ++r) {
            float mx = acc[rt][0][r];
            mx = fmaxf(mx, acc[rt][1][r]);
            mx = fmaxf(mx, acc[rt][2][r]);
            mx = fmaxf(mx, acc[rt][3][r]);
#pragma unroll
            for (int off = 1; off < 16; off <<= 1)
                mx = fmaxf(mx, __shfl_xor(mx, off));
            if (r16 == 0) wmax[wid * 64 + rt * 16 + g * 4 + r] = mx;
        }
    }
    __syncthreads();
    if (tid < BM) {
        float mx = wmax[tid];
#pragma unroll
        for (int w = 1; w < 8; ++w) mx = fmaxf(mx, wmax[w * 64 + tid]);
        int gm = m0 + tid;
        if (gm < MK) scores[gm] = mx;
    }
}

// ---------------------------------------------------------------------------
// threshold select, multi-block
// ---------------------------------------------------------------------------
__global__ void zero_hist(unsigned int* __restrict__ hist, int* __restrict__ cnt) {
    int i = blockIdx.x * 1024 + threadIdx.x;
    if (i < 8192) hist[i] = 0;
    if (i == 0) cnt[0] = 0;
}

__global__ void hist_build(const float* __restrict__ scores, unsigned int* __restrict__ hist) {
    __shared__ unsigned int lh[8192];
    for (int i = threadIdx.x; i < 8192; i += 256) lh[i] = 0;
    __syncthreads();
    for (int i = blockIdx.x * 256 + threadIdx.x; i < MK; i += gridDim.x * 256)
        atomicAdd(&lh[xform(scores[i]) >> 19], 1u);
    __syncthreads();
    for (int i = threadIdx.x; i < 8192; i += 256) {
        unsigned int c = lh[i];
        if (c) atomicAdd(&hist[i], c);
    }
}

__launch_bounds__(1024)
__global__ void find_thresh(const unsigned int* __restrict__ hist, float* __restrict__ vlo) {
    __shared__ unsigned int s0[1024], s1[1024];
    const int tid = threadIdx.x;
    unsigned int s = 0;
#pragma unroll
    for (int j = 0; j < 8; ++j) s += hist[tid * 8 + j];
    s0[tid] = s;
    __syncthreads();
    unsigned int* src = s0;
    unsigned int* dst = s1;
    for (int off = 1; off < 1024; off <<= 1) {
        unsigned int v = src[tid] + ((tid + off < 1024) ? src[tid + off] : 0u);
        __syncthreads();
        dst[tid] = v;
        __syncthreads();
        unsigned int* t = src; src = dst; dst = t;
    }
    unsigned int suf  = src[tid];
    unsigned int sufn = (tid < 1023) ? src[tid + 1] : 0u;
    if (suf >= 64u && sufn < 64u) {
        unsigned int acc = sufn;
        int b = tid * 8 + 7;
        for (;; --b) { acc += hist[b]; if (acc >= 64u) break; }
        vlo[0] = unxform(((unsigned int)b) << 19) - 1.0f;   // margin 1.0
    }
}

__global__ void collect(const float* __restrict__ scores, const float* __restrict__ vlo,
                        int* __restrict__ cidx, int* __restrict__ cnt) {
    const float t = vlo[0];
    for (int i = blockIdx.x * 256 + threadIdx.x; i < MK; i += gridDim.x * 256) {
        if (scores[i] >= t) {
            int p = atomicAdd(cnt, 1);
            if (p < CAP) cidx[p] = i;
        }
    }
}

// ---------------------------------------------------------------------------
// exact f32 rescore: one block per candidate, max over 512 queries
// ---------------------------------------------------------------------------
__launch_bounds__(256)
__global__ void rescore(const float* __restrict__ q, const float* __restrict__ a,
                        const float* __restrict__ keys,
                        const int* __restrict__ cidx, const int* __restrict__ cnt,
                        float* __restrict__ resc) {
    __shared__ float w[1024];
    __shared__ float smax[4];
    const int b = blockIdx.x;
    if (b >= cnt[0]) return;
    const int m   = cidx[b];
    const int tid = threadIdx.x;

    for (int d = tid; d < 1024; d += 256) w[d] = a[d] * keys[(size_t)m * DD + d];
    __syncthreads();

    const int wid = tid >> 6, lane = tid & 63;
    float best = -__builtin_inff();
    for (int n = wid; n < NQ; n += 4) {
        const float* qr = q + (size_t)n * DD;
        float p = 0.f;
#pragma unroll
        for (int j = 0; j < 4; ++j) {
            float4 v  = *(const float4*)(qr + lane * 4 + 256 * j);
            float4 ww = *(const float4*)(&w[lane * 4 + 256 * j]);
            p += v.x * ww.x + v.y * ww.y + v.z * ww.z + v.w * ww.w;
        }
#pragma unroll
        for (int off = 1; off < 64; off <<= 1) p += __shfl_xor(p, off);
        best = fmaxf(best, p);
    }
    if (lane == 0) smax[wid] = best;
    __syncthreads();
    if (tid == 0)
        resc[b] = fmaxf(fmaxf(smax[0], smax[1]), fmaxf(smax[2], smax[3]));
}

// ---------------------------------------------------------------------------
// final: top-64 over candidates (exact vals, tie: idx asc), softmax, gather V
// ---------------------------------------------------------------------------
__launch_bounds__(256)
__global__ void final_select(const int* __restrict__ cidx, const float* __restrict__ resc,
                             const int* __restrict__ cnt, const float* __restrict__ values,
                             float* __restrict__ out) {
    __shared__ float selw[64];
    __shared__ int   seli[64];
    const int tid = threadIdx.x;
    int nc = cnt[0];
    if (nc > CAP) nc = CAP;

    if (tid < 64) {
        const int lane = tid;
        float lv[16]; int li[16];
#pragma unroll
        for (int j = 0; j < 16; ++j) {
            int slot = lane + 64 * j;
            bool ok = slot < nc;
            lv[j] = ok ? resc[slot] : -__builtin_inff();
            li[j] = ok ? cidx[slot] : 0x7fffffff;
        }
        for (int it = 0; it < 64; ++it) {
            float bv = -__builtin_inff();
            int bg = 0x7fffffff, bj = 0;
#pragma unroll
            for (int j = 0; j < 16; ++j)
                if (lv[j] > bv || (lv[j] == bv && li[j] < bg)) { bv = lv[j]; bg = li[j]; bj = j; }
            int bcode = (lane << 4) | bj;
#pragma unroll
            for (int off = 1; off < 64; off <<= 1) {
                float ov = __shfl_xor(bv, off);
                int   og = __shfl_xor(bg, off);
                int   oc = __shfl_xor(bcode, off);
                if (ov > bv || (ov == bv && og < bg)) { bv = ov; bg = og; bcode = oc; }
            }
            if ((bcode >> 4) == lane) {
                int wj = bcode & 15;
#pragma unroll
                for (int j = 0; j < 16; ++j) if (j == wj) lv[j] = -__builtin_inff();
            }
            if (lane == 0) { selw[it] = bv; seli[it] = bg; }
        }
    }
    __syncthreads();

    if (tid < 64) {
        float x = selw[tid];
        float mx = x;
#pragma unroll
        for (int off = 1; off < 64; off <<= 1) mx = fmaxf(mx, __shfl_xor(mx, off));
        float e = expf(x - mx);
        float s = e;
#pragma unroll
        for (int off = 1; off < 64; off <<= 1) s += __shfl_xor(s, off);
        selw[tid] = e / s;
        out[DD + tid] = (float)seli[tid];
    }
    __syncthreads();

    for (int d = tid; d < DD; d += 256) {
        float accv = 0.f;
        for (int i = 0; i < 64; ++i)
            accv += selw[i] * values[(size_t)seli[i] * DD + d];
        out[d] = accv;
    }
}

// ---------------------------------------------------------------------------
extern "C" void kernel_launch(void* const* d_in, const int* in_sizes, int n_in,
                              void* d_out, int out_size, void* d_ws, size_t ws_size,
                              hipStream_t stream) {
    (void)in_sizes; (void)n_in; (void)out_size; (void)ws_size;
    const float* queries = (const float*)d_in[0];
    const float* keys    = (const float*)d_in[1];
    const float* values  = (const float*)d_in[2];
    const float* affine  = (const float*)d_in[3];
    float* out = (float*)d_out;
    char*  ws  = (char*)d_ws;

    unsigned short* kstage = (unsigned short*)(ws + KSTAGE_OFF);
    unsigned short* qstage = (unsigned short*)(ws + QSTAGE_OFF);
    float* scores = (float*)(ws + SCORES_OFF);
    int*   cidx   = (int*)(ws + CIDX_OFF);
    float* resc   = (float*)(ws + RESC_OFF);
    int*   cnt    = (int*)(ws + CNT_OFF);
    unsigned int* hist = (unsigned int*)(ws + HIST_OFF);
    float* vlo    = (float*)(ws + VLO_OFF);

    hipFuncSetAttribute((const void*)scores_gemm,
                        hipFuncAttributeMaxDynamicSharedMemorySize, GEMM_LDS);
    hipFuncSetAttribute((const void*)prep_keys,
                        hipFuncAttributeMaxDynamicSharedMemorySize, PREP_LDS);

    prep_q<<<(NKK * NQ * 4) / 256, 256, 0, stream>>>(queries, affine, qstage);
    prep_keys<<<MBLOCKS, 1024, PREP_LDS, stream>>>(keys, kstage);
    scores_gemm<<<MBLOCKS, 512, GEMM_LDS, stream>>>(kstage, qstage, scores);
    zero_hist<<<8, 1024, 0, stream>>>(hist, cnt);
    hist_build<<<64, 256, 0, stream>>>(scores, hist);
    find_thresh<<<1, 1024, 0, stream>>>(hist, vlo);
    collect<<<200, 256, 0, stream>>>(scores, vlo, cidx, cnt);
    rescore<<<CAP, 256, 0, stream>>>(queries, affine, keys, cidx, cnt, resc);
    final_select<<<1, 256, 0, stream>>>(cidx, resc, cnt, values, out);
}

// Round 8
// 444.991 us; speedup vs baseline: 1.2108x; 1.2108x over previous
//
#include <hip/hip_runtime.h>
#include <cstdint>
#include <cstddef>

// ---------------------------------------------------------------------------
// AffineMultiQueryHardAttentionEncoder
//   scores[m] = max_n ( (q[n]*a) . k[m] ), top-64, softmax, sum w_i * V[idx_i]
// R8: one-pass gemm, counted-vmcnt pipeline (T3min+T4+T14).
//   - keys f32 read ONCE inside gemm: global->reg 2 K-steps ahead (~2600cy
//     in flight > 900cy HBM), convert->ds_write 1 step ahead.
//   - B (qstage bf16, L2) via global_load_lds 1 step ahead.
//   - loop barrier = asm vmcnt(4) lgkmcnt(0) + raw s_barrier: NEVER vmcnt(0).
//     The 4 live slots are A(t+2) register loads (no LDS side effects), so
//     correctness is independent of the count.
//   - fragment-major LDS [s][g][row][16B]: all ds reads/writes linear.
// ---------------------------------------------------------------------------

typedef __attribute__((ext_vector_type(8))) short bf16x8;
typedef __attribute__((ext_vector_type(4))) float f32x4;

static constexpr int NQ = 512;
static constexpr int DD = 1024;
static constexpr int MK = 100000;
static constexpr int BM = 128;
static constexpr int KSTEPS = DD / 64;                 // 16 (BK=64)
static constexpr int MBLK = (MK + BM - 1) / BM;        // 782
static constexpr int CAP = 1024;

// workspace layout (bytes)
static constexpr size_t QSTAGE_OFF   = 0;    // [16 kk][2 s][4 g][512 q][16B] = 1 MiB
static constexpr size_t QSTAGE_BYTES = (size_t)KSTEPS * 8 * NQ * 16;
static constexpr size_t SCORES_OFF   = QSTAGE_OFF + QSTAGE_BYTES;
static constexpr size_t SCORES_BYTES = (size_t)MBLK * BM * sizeof(float);
static constexpr size_t CIDX_OFF     = SCORES_OFF + SCORES_BYTES;
static constexpr size_t RESC_OFF     = CIDX_OFF + (size_t)CAP * 4;
static constexpr size_t CNT_OFF      = RESC_OFF + (size_t)CAP * 4;
static constexpr size_t HIST_OFF     = CNT_OFF + 64;
static constexpr size_t VLO_OFF      = HIST_OFF + 8192 * 4;

// gemm LDS: A dbuf 2 x [2s][4g][128 r][16B]=16KB @0 ; B dbuf 2 x [2][4][512][16B]=64KB @32768
static constexpr int ABASE = 0;
static constexpr int BBASE = 32768;
static constexpr int GEMM_LDS = 32768 + 2 * 65536;     // 163840 = full 160KB

static __device__ __forceinline__ unsigned short f32_to_bf16_rne(float f) {
    unsigned int u = __float_as_uint(f);
    unsigned int r = (u + 0x7FFFu + ((u >> 16) & 1u)) >> 16;
    return (unsigned short)r;
}
static __device__ __forceinline__ unsigned int xform(float f) {
    unsigned int u = __float_as_uint(f);
    return u ^ ((unsigned int)((int)u >> 31) | 0x80000000u);
}
static __device__ __forceinline__ float unxform(unsigned int u) {
    unsigned int b = (u & 0x80000000u) ? (u ^ 0x80000000u) : ~u;
    return __uint_as_float(b);
}

typedef __attribute__((address_space(1))) const unsigned int g1u32;
typedef __attribute__((address_space(3))) unsigned int l3u32;
static __device__ __forceinline__ void async16(const void* g, void* l) {
    __builtin_amdgcn_global_load_lds((g1u32*)g, (l3u32*)(uintptr_t)l, 16, 0, 0);
}

// ---------------------------------------------------------------------------
// prep_q: qa = q*a -> bf16 RNE in fragment-major order:
//   qstage chunk id = ((kk*2+s)*4+g)*512 + q  holds  qa[q][kk*64+s*32+g*8 .. +7]
// ---------------------------------------------------------------------------
__global__ void prep_q(const float* __restrict__ q, const float* __restrict__ a,
                       unsigned short* __restrict__ qs) {
    int id = blockIdx.x * 256 + threadIdx.x;    // 0..65535
    int qq = id & 511;
    int j  = (id >> 9) & 7;                     // s*4+g
    int kk = id >> 12;
    int col = kk * 64 + (j >> 2) * 32 + (j & 3) * 8;

    const float* qrow = q + (size_t)qq * DD + col;
    float4 v0 = *(const float4*)(qrow);
    float4 v1 = *(const float4*)(qrow + 4);
    float4 a0 = *(const float4*)(a + col);
    float4 a1 = *(const float4*)(a + col + 4);
    float f[8] = {v0.x * a0.x, v0.y * a0.y, v0.z * a0.z, v0.w * a0.w,
                  v1.x * a1.x, v1.y * a1.y, v1.z * a1.z, v1.w * a1.w};
    bf16x8 o;
#pragma unroll
    for (int t = 0; t < 8; ++t) o[t] = (short)f32_to_bf16_rne(f[t]);
    *(bf16x8*)(qs + (size_t)id * 8) = o;
}

// ---------------------------------------------------------------------------
// prescreen GEMM + column max, counted-vmcnt pipeline
// ---------------------------------------------------------------------------
__launch_bounds__(512, 2)
__global__ void scores_gemm(const float* __restrict__ keys,
                            const unsigned short* __restrict__ qs,
                            float* __restrict__ scores) {
    extern __shared__ char smem[];
    const int tid  = threadIdx.x;
    const int wid  = tid >> 6;
    const int lane = tid & 63;
    const int g    = lane >> 4;
    const int r16  = lane & 15;
    const int wq   = wid & 3;     // query quarter (128 q)
    const int wk   = wid >> 2;    // key half (64 keys)

    // bijective XCD swizzle (m204); nwg = 782 = 8*97+6
    const int nwg = gridDim.x;
    const int qq8 = nwg >> 3, rr8 = nwg & 7;
    const int xcd = blockIdx.x & 7, loc = blockIdx.x >> 3;
    const int mb  = (xcd < rr8 ? xcd * (qq8 + 1) : rr8 * (qq8 + 1) + (xcd - rr8) * qq8) + loc;
    const int m0  = mb * BM;

    // ---- A staging geometry: thread -> (row r=tid>>2, 16 cols at c4=(tid&3)*16)
    const int ar  = tid >> 2;
    const int c4  = (tid & 3) * 16;
    int garow = m0 + ar; if (garow >= MK) garow = MK - 1;
    const float* aptr = keys + (size_t)garow * DD + c4;
    const int as  = c4 >> 5;               // s of chunk0
    const int ag  = (c4 >> 3) & 3;         // g of chunk0 (even); chunk1 = g+1
    const int aw0 = ((as * 4 + ag) * 128 + ar) * 16;   // + ABASE + buf*16384 ; +2048 for chunk1

    // ---- B staging: wave stages q in [64*wid, +64) for all 8 (s,g) chunks
    const char* qsrc = (const char*)qs + (size_t)(64 * wid + lane) * 16;
    const int   bw0  = (64 * wid) * 16;    // + BBASE + buf*65536 + j*8192

    f32x4 acc[4][8] = {};
    float4 P[4], Q[4];

#define STAGE_B(T1, BUF) do {                                                  \
    _Pragma("unroll")                                                          \
    for (int j = 0; j < 8; ++j)                                                \
        async16(qsrc + ((size_t)(T1) * 8 + j) * 8192,                          \
                smem + BBASE + (BUF) * 65536 + j * 8192 + bw0);                \
} while (0)

#define LOAD_A(TT, R) do {                                                     \
    int tA_ = (TT) < 15 ? (TT) : 15;                                           \
    _Pragma("unroll")                                                          \
    for (int i = 0; i < 4; ++i)                                                \
        R[i] = *(const float4*)(aptr + tA_ * 64 + i * 4);                      \
} while (0)

#define WRITE_A(R, BUF) do {                                                   \
    bf16x8 o0, o1;                                                             \
    _Pragma("unroll")                                                          \
    for (int i = 0; i < 4; ++i) {                                              \
        o0[i]     = (short)f32_to_bf16_rne(R[0][i]);                           \
        o0[i + 4] = (short)f32_to_bf16_rne(R[1][i]);                           \
        o1[i]     = (short)f32_to_bf16_rne(R[2][i]);                           \
        o1[i + 4] = (short)f32_to_bf16_rne(R[3][i]);                           \
    }                                                                          \
    *(bf16x8*)(smem + ABASE + (BUF) * 16384 + aw0)        = o0;                \
    *(bf16x8*)(smem + ABASE + (BUF) * 16384 + aw0 + 2048) = o1;                \
} while (0)

#define COMPUTE(BUF) do {                                                      \
    _Pragma("unroll")                                                          \
    for (int s = 0; s < 2; ++s) {                                              \
        bf16x8 af[4], bf[8];                                                   \
        _Pragma("unroll")                                                      \
        for (int rt = 0; rt < 4; ++rt)                                         \
            af[rt] = *(const bf16x8*)(smem + ABASE + (BUF) * 16384 +           \
                ((s * 4 + g) * 128 + wk * 64 + rt * 16 + r16) * 16);           \
        _Pragma("unroll")                                                      \
        for (int ct = 0; ct < 8; ++ct)                                         \
            bf[ct] = *(const bf16x8*)(smem + BBASE + (BUF) * 65536 +           \
                (s * 4 + g) * 8192 + (wq * 128 + ct * 16 + r16) * 16);         \
        __builtin_amdgcn_s_setprio(1);                                         \
        _Pragma("unroll")                                                      \
        for (int rt = 0; rt < 4; ++rt)                                         \
            _Pragma("unroll")                                                  \
            for (int ct = 0; ct < 8; ++ct)                                     \
                acc[rt][ct] = __builtin_amdgcn_mfma_f32_16x16x32_bf16(         \
                    af[rt], bf[ct], acc[rt][ct], 0, 0, 0);                     \
        __builtin_amdgcn_s_setprio(0);                                         \
    }                                                                          \
} while (0)

#define PIPE_BARRIER() do {                                                    \
    asm volatile("s_waitcnt vmcnt(4) lgkmcnt(0)" ::: "memory");                \
    __builtin_amdgcn_s_barrier();                                              \
    asm volatile("" ::: "memory");                                             \
} while (0)

// iter t: stage B(t+1)->buf[nxt]; load A(t+2)->RL; compute buf[cur];
//         convert RC (=A(t+1)) -> ds_write buf[nxt]; counted barrier.
#define ITER(T, RC, RL) do {                                                   \
    const int cur_ = (T) & 1, nxt_ = cur_ ^ 1;                                 \
    STAGE_B((T) + 1, nxt_);                                                    \
    asm volatile("" ::: "memory");  /* pin: B-glds issue before A-loads */     \
    LOAD_A((T) + 2, RL);                                                       \
    COMPUTE(cur_);                                                             \
    WRITE_A(RC, nxt_);                                                         \
    PIPE_BARRIER();                                                            \
} while (0)

    // ---- prologue: B(0)+A(0)->buf0, A(1) in flight
    STAGE_B(0, 0);
    asm volatile("" ::: "memory");
    LOAD_A(0, P);
    LOAD_A(1, Q);
    WRITE_A(P, 0);          // compiler waits A(0); B(0) (older) drains too
    PIPE_BARRIER();         // leaves A(1) in flight

    for (int t2 = 0; t2 < 7; ++t2) {
        ITER(2 * t2,     Q, P);
        ITER(2 * t2 + 1, P, Q);
    }
    ITER(14, Q, P);

    // ---- epilogue K-step 15 (buf1), then full drain
    COMPUTE(1);
    __syncthreads();

#undef STAGE_B
#undef LOAD_A
#undef WRITE_A
#undef COMPUTE
#undef PIPE_BARRIER
#undef ITER

    // ---- epilogue: max over queries. acc[rt][ct][r]: key = wk*64+rt*16+g*4+r,
    // query = wq*128 + ct*16 + r16. Reduce over ct then r16, fold wq via LDS.
    float* wmax = (float*)smem;   // [4 wq][128 keys]
#pragma unroll
    for (int rt = 0; rt < 4; ++rt) {
#pragma unroll
        for (int r = 0; r < 4; ++r) {
            float mx = acc[rt][0][r];
#pragma unroll
            for (int ct = 1; ct < 8; ++ct) mx = fmaxf(mx, acc[rt][ct][r]);
#pragma unroll
            for (int off = 1; off < 16; off <<= 1)
                mx = fmaxf(mx, __shfl_xor(mx, off));
            if (r16 == 0) wmax[wq * 128 + wk * 64 + rt * 16 + g * 4 + r] = mx;
        }
    }
    __syncthreads();
    if (tid < BM) {
        float mx = fmaxf(fmaxf(wmax[tid], wmax[128 + tid]),
                         fmaxf(wmax[256 + tid], wmax[384 + tid]));
        int gm = m0 + tid;
        if (gm < MK) scores[gm] = mx;
    }
}

// ---------------------------------------------------------------------------
// threshold select, multi-block
// ---------------------------------------------------------------------------
__global__ void zero_hist(unsigned int* __restrict__ hist, int* __restrict__ cnt) {
    int i = blockIdx.x * 1024 + threadIdx.x;
    if (i < 8192) hist[i] = 0;
    if (i == 0) cnt[0] = 0;
}

__global__ void hist_build(const float* __restrict__ scores, unsigned int* __restrict__ hist) {
    __shared__ unsigned int lh[8192];
    for (int i = threadIdx.x; i < 8192; i += 256) lh[i] = 0;
    __syncthreads();
    for (int i = blockIdx.x * 256 + threadIdx.x; i < MK; i += gridDim.x * 256)
        atomicAdd(&lh[xform(scores[i]) >> 19], 1u);
    __syncthreads();
    for (int i = threadIdx.x; i < 8192; i += 256) {
        unsigned int c = lh[i];
        if (c) atomicAdd(&hist[i], c);
    }
}

__launch_bounds__(1024)
__global__ void find_thresh(const unsigned int* __restrict__ hist, float* __restrict__ vlo) {
    __shared__ unsigned int s0[1024], s1[1024];
    const int tid = threadIdx.x;
    unsigned int s = 0;
#pragma unroll
    for (int j = 0; j < 8; ++j) s += hist[tid * 8 + j];
    s0[tid] = s;
    __syncthreads();
    unsigned int* src = s0;
    unsigned int* dst = s1;
    for (int off = 1; off < 1024; off <<= 1) {
        unsigned int v = src[tid] + ((tid + off < 1024) ? src[tid + off] : 0u);
        __syncthreads();
        dst[tid] = v;
        __syncthreads();
        unsigned int* t = src; src = dst; dst = t;
    }
    unsigned int suf  = src[tid];
    unsigned int sufn = (tid < 1023) ? src[tid + 1] : 0u;
    if (suf >= 64u && sufn < 64u) {
        unsigned int acc = sufn;
        int b = tid * 8 + 7;
        for (;; --b) { acc += hist[b]; if (acc >= 64u) break; }
        vlo[0] = unxform(((unsigned int)b) << 19) - 1.0f;   // margin 1.0
    }
}

__global__ void collect(const float* __restrict__ scores, const float* __restrict__ vlo,
                        int* __restrict__ cidx, int* __restrict__ cnt) {
    const float t = vlo[0];
    for (int i = blockIdx.x * 256 + threadIdx.x; i < MK; i += gridDim.x * 256) {
        if (scores[i] >= t) {
            int p = atomicAdd(cnt, 1);
            if (p < CAP) cidx[p] = i;
        }
    }
}

// ---------------------------------------------------------------------------
// exact f32 rescore: one block per candidate, max over 512 queries
// ---------------------------------------------------------------------------
__launch_bounds__(256)
__global__ void rescore(const float* __restrict__ q, const float* __restrict__ a,
                        const float* __restrict__ keys,
                        const int* __restrict__ cidx, const int* __restrict__ cnt,
                        float* __restrict__ resc) {
    __shared__ float w[1024];
    __shared__ float smax[4];
    const int b = blockIdx.x;
    if (b >= cnt[0]) return;
    const int m   = cidx[b];
    const int tid = threadIdx.x;

    for (int d = tid; d < 1024; d += 256) w[d] = a[d] * keys[(size_t)m * DD + d];
    __syncthreads();

    const int wid = tid >> 6, lane = tid & 63;
    float best = -__builtin_inff();
    for (int n = wid; n < NQ; n += 4) {
        const float* qr = q + (size_t)n * DD;
        float p = 0.f;
#pragma unroll
        for (int j = 0; j < 4; ++j) {
            float4 v  = *(const float4*)(qr + lane * 4 + 256 * j);
            float4 ww = *(const float4*)(&w[lane * 4 + 256 * j]);
            p += v.x * ww.x + v.y * ww.y + v.z * ww.z + v.w * ww.w;
        }
#pragma unroll
        for (int off = 1; off < 64; off <<= 1) p += __shfl_xor(p, off);
        best = fmaxf(best, p);
    }
    if (lane == 0) smax[wid] = best;
    __syncthreads();
    if (tid == 0)
        resc[b] = fmaxf(fmaxf(smax[0], smax[1]), fmaxf(smax[2], smax[3]));
}

// ---------------------------------------------------------------------------
// final: top-64 over candidates (exact vals, tie: idx asc), softmax, gather V
// ---------------------------------------------------------------------------
__launch_bounds__(256)
__global__ void final_select(const int* __restrict__ cidx, const float* __restrict__ resc,
                             const int* __restrict__ cnt, const float* __restrict__ values,
                             float* __restrict__ out) {
    __shared__ float selw[64];
    __shared__ int   seli[64];
    const int tid = threadIdx.x;
    int nc = cnt[0];
    if (nc > CAP) nc = CAP;

    if (tid < 64) {
        const int lane = tid;
        float lv[16]; int li[16];
#pragma unroll
        for (int j = 0; j < 16; ++j) {
            int slot = lane + 64 * j;
            bool ok = slot < nc;
            lv[j] = ok ? resc[slot] : -__builtin_inff();
            li[j] = ok ? cidx[slot] : 0x7fffffff;
        }
        for (int it = 0; it < 64; ++it) {
            float bv = -__builtin_inff();
            int bg = 0x7fffffff, bj = 0;
#pragma unroll
            for (int j = 0; j < 16; ++j)
                if (lv[j] > bv || (lv[j] == bv && li[j] < bg)) { bv = lv[j]; bg = li[j]; bj = j; }
            int bcode = (lane << 4) | bj;
#pragma unroll
            for (int off = 1; off < 64; off <<= 1) {
                float ov = __shfl_xor(bv, off);
                int   og = __shfl_xor(bg, off);
                int   oc = __shfl_xor(bcode, off);
                if (ov > bv || (ov == bv && og < bg)) { bv = ov; bg = og; bcode = oc; }
            }
            if ((bcode >> 4) == lane) {
                int wj = bcode & 15;
#pragma unroll
                for (int j = 0; j < 16; ++j) if (j == wj) lv[j] = -__builtin_inff();
            }
            if (lane == 0) { selw[it] = bv; seli[it] = bg; }
        }
    }
    __syncthreads();

    if (tid < 64) {
        float x = selw[tid];
        float mx = x;
#pragma unroll
        for (int off = 1; off < 64; off <<= 1) mx = fmaxf(mx, __shfl_xor(mx, off));
        float e = expf(x - mx);
        float s = e;
#pragma unroll
        for (int off = 1; off < 64; off <<= 1) s += __shfl_xor(s, off);
        selw[tid] = e / s;
        out[DD + tid] = (float)seli[tid];
    }
    __syncthreads();

    for (int d = tid; d < DD; d += 256) {
        float accv = 0.f;
        for (int i = 0; i < 64; ++i)
            accv += selw[i] * values[(size_t)seli[i] * DD + d];
        out[d] = accv;
    }
}

// ---------------------------------------------------------------------------
extern "C" void kernel_launch(void* const* d_in, const int* in_sizes, int n_in,
                              void* d_out, int out_size, void* d_ws, size_t ws_size,
                              hipStream_t stream) {
    (void)in_sizes; (void)n_in; (void)out_size; (void)ws_size;
    const float* queries = (const float*)d_in[0];
    const float* keys    = (const float*)d_in[1];
    const float* values  = (const float*)d_in[2];
    const float* affine  = (const float*)d_in[3];
    float* out = (float*)d_out;
    char*  ws  = (char*)d_ws;

    unsigned short* qstage = (unsigned short*)(ws + QSTAGE_OFF);
    float* scores = (float*)(ws + SCORES_OFF);
    int*   cidx   = (int*)(ws + CIDX_OFF);
    float* resc   = (float*)(ws + RESC_OFF);
    int*   cnt    = (int*)(ws + CNT_OFF);
    unsigned int* hist = (unsigned int*)(ws + HIST_OFF);
    float* vlo    = (float*)(ws + VLO_OFF);

    hipFuncSetAttribute((const void*)scores_gemm,
                        hipFuncAttributeMaxDynamicSharedMemorySize, GEMM_LDS);

    prep_q<<<256, 256, 0, stream>>>(queries, affine, qstage);
    scores_gemm<<<MBLK, 512, GEMM_LDS, stream>>>(keys, qstage, scores);
    zero_hist<<<8, 1024, 0, stream>>>(hist, cnt);
    hist_build<<<64, 256, 0, stream>>>(scores, hist);
    find_thresh<<<1, 1024, 0, stream>>>(hist, vlo);
    collect<<<200, 256, 0, stream>>>(scores, vlo, cidx, cnt);
    rescore<<<CAP, 256, 0, stream>>>(queries, affine, keys, cidx, cnt, resc);
    final_select<<<1, 256, 0, stream>>>(cidx, resc, cnt, values, out);
}